// Round 3
// baseline (1644.932 us; speedup 1.0000x reference)
//
#include <hip/hip_runtime.h>
#include <math.h>

#define D 2048
#define E 64
#define EH 32                 // experts per wave (half)
#define TOK 64                // tokens per block (lane = token)
#define THREADS 1024          // 16 waves = 8 K-chunks x 2 expert halves
#define NKC 8
#define KCH (D / NKC)         // 256

// W row slice (32 floats) via per-lane global_load_dwordx4 x8.
// Address carries an opaque VGPR zero so the compiler CANNOT scalarize to
// s_load: vmcnt loads retire in-order -> partial waits, unlike lgkmcnt SMEM
// which forces a full drain before first use.
__device__ __forceinline__ void wloadv(float4 (&dst)[8], const float* p) {
#pragma unroll
    for (int c = 0; c < 8; ++c) dst[c] = *(const float4*)(p + 4 * c);
}

// 32 FMAs: acc[e] += xj * wb[e]  (all-VGPR v_fmac)
__device__ __forceinline__ void fmagrp(float (&acc)[EH], float xj,
                                       const float4 (&wb)[8]) {
#pragma unroll
    for (int c = 0; c < 8; ++c) {
        acc[4*c+0] = fmaf(xj, wb[c].x, acc[4*c+0]);
        acc[4*c+1] = fmaf(xj, wb[c].y, acc[4*c+1]);
        acc[4*c+2] = fmaf(xj, wb[c].z, acc[4*c+2]);
        acc[4*c+3] = fmaf(xj, wb[c].w, acc[4*c+3]);
    }
}

// Reduction-tile IO. Tile = [64 tokens][32 floats]; lane owns its row.
// Column-slot swizzle (c+lane)&7 spreads b128 ops over all 32 banks.
__device__ __forceinline__ void tile_write(float* base, const float (&acc)[EH],
                                           int lane) {
#pragma unroll
    for (int c = 0; c < 8; ++c) {
        int s = (c + lane) & 7;
        float4 v = {acc[4 * c], acc[4 * c + 1], acc[4 * c + 2], acc[4 * c + 3]};
        *(float4*)(base + lane * EH + s * 4) = v;
    }
}

__device__ __forceinline__ void tile_add(const float* base, float (&acc)[EH],
                                         int lane) {
#pragma unroll
    for (int c = 0; c < 8; ++c) {
        int s = (c + lane) & 7;
        float4 v = *(const float4*)(base + lane * EH + s * 4);
        acc[4 * c] += v.x; acc[4 * c + 1] += v.y;
        acc[4 * c + 2] += v.z; acc[4 * c + 3] += v.w;
    }
}

// Pin occupancy to exactly 4 waves/SIMD: VGPR budget 128, and the allocator
// cannot "buy" unattainable occupancy by spilling (the 16-wave block caps us
// at 4 waves/SIMD regardless). Round-2 post-mortem: launch_bounds(.,4) is only
// a LOWER bound -> compiler allocated 64 VGPRs + 3.25 GB of scratch writes.
__global__ __launch_bounds__(THREADS)
__attribute__((amdgpu_waves_per_eu(4, 4)))
void gating_kernel(const float* __restrict__ x,
                   const float* __restrict__ W,
                   const float* __restrict__ Bv,
                   float* __restrict__ out)
{
    // LDS (64 KB): tree tiles 0..7 at w*8KB. After the final tree barrier,
    // tiles 0..1 area is reused for logits [64][65] and the top-2 arrays.
    __shared__ __align__(16) char smem[65536];

    const int tid  = threadIdx.x;
    const int lane = tid & 63;
    const int w    = __builtin_amdgcn_readfirstlane(tid >> 6);
    const int eh   = w & 1;          // expert half (32 experts)
    const int kc   = w >> 1;         // K-chunk 0..7
    const int tok0 = blockIdx.x * TOK;

    const float* xrow = x + (size_t)(tok0 + lane) * D + kc * KCH;  // per-lane

    // Opaque zero in a VGPR -> W address is "divergent" -> global_load, not s_load.
    int voff = 0;
    asm volatile("" : "+v"(voff));
    const float* wk = W + (size_t)kc * KCH * E + eh * EH + voff;

    float acc[EH];
#pragma unroll
    for (int e = 0; e < EH; ++e) acc[e] = 0.f;

    // ---- K-loop: W 2-row double buffer in VGPRs, x per-lane float4 ----
    float4 wb[2][8];
    wloadv(wb[0], wk);                // row 0
    wloadv(wb[1], wk + E);            // row 1
    float4 xv = *(const float4*)(xrow);
    float4 xn = *(const float4*)(xrow + 4);

#pragma unroll 1
    for (int k4 = 0; k4 < KCH / 4; ++k4) {
        float4 xc = xv; xv = xn;
        int nx = (k4 + 2 < KCH / 4) ? k4 + 2 : KCH / 4 - 1;
        xn = *(const float4*)(xrow + nx * 4);
#pragma unroll
        for (int j = 0; j < 4; ++j) {
            const float xj = j == 0 ? xc.x : j == 1 ? xc.y
                           : j == 2 ? xc.z : xc.w;
            fmagrp(acc, xj, wb[j & 1]);        // uses row 4*k4+j
            int r = 4 * k4 + j + 2;            // prefetch 2 rows ahead
            if (r > KCH - 1) r = KCH - 1;
            wloadv(wb[j & 1], wk + (size_t)r * E);
        }
    }

    // ---- cross-wave K-reduction: 3-level tree, pairing (kc, kc+step) ----
    float* tiles = (float*)smem;               // tile i at i*2048 floats
    __syncthreads();
    if (w >= 8) tile_write(tiles + (w - 8) * 2048, acc, lane);
    __syncthreads();
    if (w < 8)  tile_add(tiles + w * 2048, acc, lane);
    __syncthreads();
    if (w >= 4 && w < 8) tile_write(tiles + (w - 4) * 2048, acc, lane);
    __syncthreads();
    if (w < 4)  tile_add(tiles + w * 2048, acc, lane);
    __syncthreads();
    if (w == 2 || w == 3) tile_write(tiles + (w - 2) * 2048, acc, lane);
    __syncthreads();
    if (w < 2)  tile_add(tiles + w * 2048, acc, lane);   // w0: eh0, w1: eh1 full
    __syncthreads();                                     // tiles now dead

    float* logits = (float*)smem;              // [64][65]
    float* sw1 = (float*)(smem + 16640);
    float* sw2 = (float*)(smem + 16896);
    int*   si1 = (int*)  (smem + 17152);
    int*   si2 = (int*)  (smem + 17408);

    if (w < 2) {                               // write full logits tile
#pragma unroll
        for (int e = 0; e < EH; ++e)
            logits[lane * 65 + eh * EH + e] = acc[e];
    }
    __syncthreads();

    if (w == 0) {
        // lane = token: top-2 scan (+bias). Strict '>' matches top_k ties.
        float m1 = -3.4e38f, m2 = -3.4e38f;
        int i1 = 0, i2 = 0;
#pragma unroll
        for (int e = 0; e < E; ++e) {
            float v = logits[lane * 65 + e] + Bv[e];
            if (v > m1)      { m2 = m1; i2 = i1; m1 = v; i1 = e; }
            else if (v > m2) { m2 = v; i2 = e; }
        }
        float p = 1.0f / (1.0f + expf(m2 - m1));   // stable: m2 <= m1
        sw1[lane] = p; sw2[lane] = 1.0f - p;
        si1[lane] = i1; si2[lane] = i2;
    }
    __syncthreads();

    // ---- coalesced float4 store of the 64x64 tile (1024 float4) ----
    float4* o4 = (float4*)(out + (size_t)tok0 * E);
    {
        int idx = tid;                  // 0..1023
        int tl  = idx >> 4;             // token 0..63
        int e0  = (idx & 15) * 4;
        int a1 = si1[tl], a2 = si2[tl];
        float v1 = sw1[tl], v2 = sw2[tl];
        float4 v;
        v.x = (e0 + 0 == a1) ? v1 : (e0 + 0 == a2) ? v2 : 0.0f;
        v.y = (e0 + 1 == a1) ? v1 : (e0 + 1 == a2) ? v2 : 0.0f;
        v.z = (e0 + 2 == a1) ? v1 : (e0 + 2 == a2) ? v2 : 0.0f;
        v.w = (e0 + 3 == a1) ? v1 : (e0 + 3 == a2) ? v2 : 0.0f;
        o4[idx] = v;
    }
}

extern "C" void kernel_launch(void* const* d_in, const int* in_sizes, int n_in,
                              void* d_out, int out_size, void* d_ws, size_t ws_size,
                              hipStream_t stream) {
    const float* x = (const float*)d_in[0];
    const float* W = (const float*)d_in[1];
    const float* b = (const float*)d_in[2];
    float* out = (float*)d_out;

    const int tokens = in_sizes[0] / D;      // 16384
    const int blocks = tokens / TOK;         // 256

    gating_kernel<<<blocks, THREADS, 0, stream>>>(x, W, b, out);
}

// Round 4
// 447.739 us; speedup vs baseline: 3.6739x; 3.6739x over previous
//
#include <hip/hip_runtime.h>
#include <math.h>

#define D 2048
#define E 64
#define EQ 16                 // experts per wave (quarter)
#define TOK 64                // tokens per block (lane = token)
#define THREADS 1024          // 16 waves = 4 K-chunks x 4 expert quarters
#define NKC 4
#define KCH (D / NKC)         // 512
#define TP 20                 // tree-tile row stride (floats): measured 0 LDS conflicts

// W row slice (16 floats) via uniform-address global_load_dwordx4 x4.
// The address carries an opaque VGPR zero so the compiler CANNOT scalarize to
// s_load: SMEM is out-of-order (full lgkmcnt drain before first use, the
// original 25%-duty stall); global loads retire in-order on vmcnt -> the
// compiler emits partial waits and the 2-row double buffer actually pipelines.
__device__ __forceinline__ void wloadv(float4 (&dst)[4], const float* p) {
#pragma unroll
    for (int c = 0; c < 4; ++c) dst[c] = *(const float4*)(p + 4 * c);
}

// 16 FMAs: acc[e] += xj * wb[e]  (all-VGPR v_fmac)
__device__ __forceinline__ void fmagrp(float (&acc)[EQ], float xj,
                                       const float4 (&wb)[4]) {
#pragma unroll
    for (int c = 0; c < 4; ++c) {
        acc[4*c+0] = fmaf(xj, wb[c].x, acc[4*c+0]);
        acc[4*c+1] = fmaf(xj, wb[c].y, acc[4*c+1]);
        acc[4*c+2] = fmaf(xj, wb[c].z, acc[4*c+2]);
        acc[4*c+3] = fmaf(xj, wb[c].w, acc[4*c+3]);
    }
}

// Reduction-tile IO. Tile = [64 tokens][16 floats @ stride TP=20]; lane owns
// its row. Quad-bank index = (5*lane + c) % 8 -> even spread, no swizzle
// needed (round-1 kernel with this exact pattern measured SQ_LDS_BANK_CONFLICT=0).
__device__ __forceinline__ void tile_write(float* t, const float (&a)[EQ], int lane) {
    float4* p = (float4*)(t + lane * TP);
#pragma unroll
    for (int c = 0; c < 4; ++c) {
        float4 v = {a[4*c], a[4*c+1], a[4*c+2], a[4*c+3]};
        p[c] = v;
    }
}

__device__ __forceinline__ void tile_add(const float* t, float (&a)[EQ], int lane) {
    const float4* p = (const float4*)(t + lane * TP);
#pragma unroll
    for (int c = 0; c < 4; ++c) {
        float4 v = p[c];
        a[4*c] += v.x; a[4*c+1] += v.y; a[4*c+2] += v.z; a[4*c+3] += v.w;
    }
}

// Live set sized to fit the allocator's 64-VGPR target (8-waves/EU class):
// wb[2][4]=32 + acc[16] + x dbuf 12 + addr ~4 = ~64. Rounds 1-3 proved the
// backend pins 64 VGPRs regardless of launch_bounds/waves_per_eu and spills
// anything above it (3-4 GB of scratch traffic). Fit, don't fight.
__global__ __launch_bounds__(THREADS, 4)
void gating_kernel(const float* __restrict__ x,
                   const float* __restrict__ W,
                   const float* __restrict__ Bv,
                   float* __restrict__ out)
{
    // LDS: 8 tree tiles at t*64*TP floats (40 KB). After the final tree
    // barrier the region is reused for logits [64][65] + top-2 arrays.
    __shared__ __align__(16) float smem[10240];

    const int tid  = threadIdx.x;
    const int lane = tid & 63;
    const int w    = __builtin_amdgcn_readfirstlane(tid >> 6);
    const int eq   = w & 3;          // expert quarter (16 experts)
    const int kc   = w >> 2;         // K-chunk 0..3 (512 rows)
    const int tok0 = blockIdx.x * TOK;

    const float* xrow = x + (size_t)(tok0 + lane) * D + kc * KCH;  // per-lane

    // Opaque zero in a VGPR -> W address is "divergent" -> global_load, not s_load.
    int voff = 0;
    asm volatile("" : "+v"(voff));
    const float* wk = W + (size_t)kc * KCH * E + eq * EQ + voff;

    float acc[EQ];
#pragma unroll
    for (int e = 0; e < EQ; ++e) acc[e] = 0.f;

    // ---- K-loop: W 2-row double buffer in VGPRs, x per-lane float4 ----
    float4 wb[2][4];
    wloadv(wb[0], wk);                // row 0
    wloadv(wb[1], wk + E);            // row 1
    float4 xv = *(const float4*)(xrow);
    float4 xn = *(const float4*)(xrow + 4);

#pragma unroll 1
    for (int k4 = 0; k4 < KCH / 4; ++k4) {
        float4 xc = xv; xv = xn;
        int nx = (k4 + 2 < KCH / 4) ? k4 + 2 : KCH / 4 - 1;
        xn = *(const float4*)(xrow + nx * 4);
#pragma unroll
        for (int j = 0; j < 4; ++j) {
            const float xj = j == 0 ? xc.x : j == 1 ? xc.y
                           : j == 2 ? xc.z : xc.w;
            fmagrp(acc, xj, wb[j & 1]);        // uses row 4*k4+j
            int r = 4 * k4 + j + 2;            // prefetch 2 rows ahead
            if (r > KCH - 1) r = KCH - 1;
            wloadv(wb[j & 1], wk + (size_t)r * E);
        }
    }

    // ---- cross-wave K-reduction: 2-level tree, pairing (kc, kc+step) ----
    // w = kc*4 + eq. Step 1: kc{2,3} -> tiles[w-8], kc{0,1} add tiles[w].
    // Step 2: kc1 -> tiles[w-4], kc0 adds. Waves 0..3 then hold full sums.
    float* tiles = smem;                       // tile t at t*1280 floats
    __syncthreads();
    if (w >= 8) tile_write(tiles + (w - 8) * 64 * TP, acc, lane);
    __syncthreads();
    if (w < 8)  tile_add(tiles + w * 64 * TP, acc, lane);
    __syncthreads();
    if (w >= 4 && w < 8) tile_write(tiles + (w - 4) * 64 * TP, acc, lane);
    __syncthreads();
    if (w < 4)  tile_add(tiles + w * 64 * TP, acc, lane);
    __syncthreads();                                     // tiles now dead

    float* logits = smem;                      // [64][65]
    float* sw1 = (float*)((char*)smem + 16640);
    float* sw2 = (float*)((char*)smem + 16896);
    int*   si1 = (int*)  ((char*)smem + 17152);
    int*   si2 = (int*)  ((char*)smem + 17408);

    if (w < 4) {                               // write full logits tile
#pragma unroll
        for (int e = 0; e < EQ; ++e)
            logits[lane * 65 + eq * EQ + e] = acc[e];
    }
    __syncthreads();

    if (w == 0) {
        // lane = token: top-2 scan (+bias). Strict '>' matches top_k ties.
        float m1 = -3.4e38f, m2 = -3.4e38f;
        int i1 = 0, i2 = 0;
#pragma unroll
        for (int e = 0; e < E; ++e) {
            float v = logits[lane * 65 + e] + Bv[e];
            if (v > m1)      { m2 = m1; i2 = i1; m1 = v; i1 = e; }
            else if (v > m2) { m2 = v; i2 = e; }
        }
        float p = 1.0f / (1.0f + expf(m2 - m1));   // stable: m2 <= m1
        sw1[lane] = p; sw2[lane] = 1.0f - p;
        si1[lane] = i1; si2[lane] = i2;
    }
    __syncthreads();

    // ---- coalesced float4 store of the 64x64 tile (1024 float4) ----
    float4* o4 = (float4*)(out + (size_t)tok0 * E);
    {
        int idx = tid;                  // 0..1023
        int tl  = idx >> 4;             // token 0..63
        int e0  = (idx & 15) * 4;
        int a1 = si1[tl], a2 = si2[tl];
        float v1 = sw1[tl], v2 = sw2[tl];
        float4 v;
        v.x = (e0 + 0 == a1) ? v1 : (e0 + 0 == a2) ? v2 : 0.0f;
        v.y = (e0 + 1 == a1) ? v1 : (e0 + 1 == a2) ? v2 : 0.0f;
        v.z = (e0 + 2 == a1) ? v1 : (e0 + 2 == a2) ? v2 : 0.0f;
        v.w = (e0 + 3 == a1) ? v1 : (e0 + 3 == a2) ? v2 : 0.0f;
        o4[idx] = v;
    }
}

extern "C" void kernel_launch(void* const* d_in, const int* in_sizes, int n_in,
                              void* d_out, int out_size, void* d_ws, size_t ws_size,
                              hipStream_t stream) {
    const float* x = (const float*)d_in[0];
    const float* W = (const float*)d_in[1];
    const float* b = (const float*)d_in[2];
    float* out = (float*)d_out;

    const int tokens = in_sizes[0] / D;      // 16384
    const int blocks = tokens / TOK;         // 256

    gating_kernel<<<blocks, THREADS, 0, stream>>>(x, W, b, out);
}